// Round 1
// baseline (753.538 us; speedup 1.0000x reference)
//
#include <hip/hip_runtime.h>

#define N_ZONE 100000
#define E_ZONE 2000000
#define N_OUT  50000
#define E_OUT  1000000
#define N_GND  50000
#define E_GND  1000000
#define HID    64

// workspace layout (floats):
//   [0,                 200000)  deg -> dinv  (zone | outdoor | ground)
//   [200000,            400000)  s_zone   (N_ZONE*2)
//   [400000,            550000)  s_out    (N_OUT*3)
//   [550000,            600000)  s_gnd    (N_GND*1)
#define WS_DEG_Z   0
#define WS_DEG_O   (N_ZONE)
#define WS_DEG_G   (N_ZONE + N_OUT)
#define WS_DEG_TOT (N_ZONE + N_OUT + N_GND)            // 200000
#define WS_S_Z     WS_DEG_TOT                          // 200000
#define WS_S_O     (WS_S_Z + N_ZONE * 2)               // 400000
#define WS_S_G     (WS_S_O + N_OUT * 3)                // 550000
#define WS_TOT     (WS_S_G + N_GND * 1)                // 600000

__global__ void k_init(float* __restrict__ ws) {
    int i = blockIdx.x * blockDim.x + threadIdx.x;
    if (i < WS_TOT) ws[i] = (i < WS_DEG_TOT) ? 1.0f : 0.0f;  // deg starts at 1 (self loop)
}

// pass 1: deg[col] += w   (edge-parallel, all 3 graphs fused)
__global__ void k_deg(const int* __restrict__ eiz, const float* __restrict__ wz,
                      const int* __restrict__ eio, const float* __restrict__ wo,
                      const int* __restrict__ eig, const float* __restrict__ wg,
                      float* __restrict__ ws) {
    int t = blockIdx.x * blockDim.x + threadIdx.x;
    if (t < E_ZONE) {
        atomicAdd(ws + WS_DEG_Z + eiz[E_ZONE + t], wz[t]);
    } else if (t < E_ZONE + E_OUT) {
        int e = t - E_ZONE;
        atomicAdd(ws + WS_DEG_O + eio[E_OUT + e], wo[e]);
    } else if (t < E_ZONE + E_OUT + E_GND) {
        int e = t - E_ZONE - E_OUT;
        atomicAdd(ws + WS_DEG_G + eig[E_GND + e], wg[e]);
    }
}

// pass 2: dinv = rsqrt(deg), in place
__global__ void k_dinv(float* __restrict__ ws) {
    int i = blockIdx.x * blockDim.x + threadIdx.x;
    if (i < WS_DEG_TOT) ws[i] = 1.0f / sqrtf(ws[i]);
}

// pass 3: s[col][k] += dinv[row]*w*dinv[col] * x[row][k]   (edge-parallel, fused)
__global__ void k_scatter(const int* __restrict__ eiz, const float* __restrict__ wz, const float* __restrict__ xz,
                          const int* __restrict__ eio, const float* __restrict__ wo, const float* __restrict__ xo,
                          const int* __restrict__ eig, const float* __restrict__ wg, const float* __restrict__ xg,
                          float* __restrict__ ws) {
    int t = blockIdx.x * blockDim.x + threadIdx.x;
    if (t < E_ZONE) {
        int row = eiz[t], col = eiz[E_ZONE + t];
        float n = ws[WS_DEG_Z + row] * wz[t] * ws[WS_DEG_Z + col];
        atomicAdd(ws + WS_S_Z + col * 2 + 0, n * xz[row * 2 + 0]);
        atomicAdd(ws + WS_S_Z + col * 2 + 1, n * xz[row * 2 + 1]);
    } else if (t < E_ZONE + E_OUT) {
        int e = t - E_ZONE;
        int row = eio[e], col = eio[E_OUT + e];
        float n = ws[WS_DEG_O + row] * wo[e] * ws[WS_DEG_O + col];
        atomicAdd(ws + WS_S_O + col * 3 + 0, n * xo[row * 3 + 0]);
        atomicAdd(ws + WS_S_O + col * 3 + 1, n * xo[row * 3 + 1]);
        atomicAdd(ws + WS_S_O + col * 3 + 2, n * xo[row * 3 + 2]);
    } else if (t < E_ZONE + E_OUT + E_GND) {
        int e = t - E_ZONE - E_OUT;
        int row = eig[e], col = eig[E_GND + e];
        float n = ws[WS_DEG_G + row] * wg[e] * ws[WS_DEG_G + col];
        atomicAdd(ws + WS_S_G + col, n * xg[row]);
    }
}

// pass 4: out = relu((s + dinv^2 * x) @ W + b), one thread per output element
__global__ void k_final(const float* __restrict__ ws,
                        const float* __restrict__ xz, const float* __restrict__ Wz, const float* __restrict__ bz,
                        const float* __restrict__ xo, const float* __restrict__ Wo, const float* __restrict__ bo,
                        const float* __restrict__ xg, const float* __restrict__ Wg, const float* __restrict__ bg,
                        float* __restrict__ out) {
    int t = blockIdx.x * blockDim.x + threadIdx.x;
    const int TZ = N_ZONE * HID;            // 6.4M
    const int TO = TZ + N_OUT * HID;        // 9.6M
    const int TG = TO + N_GND * HID;        // 12.8M
    if (t < TZ) {
        int i = t >> 6, j = t & 63;
        float di = ws[WS_DEG_Z + i], d2 = di * di;
        float t0 = ws[WS_S_Z + i * 2 + 0] + d2 * xz[i * 2 + 0];
        float t1 = ws[WS_S_Z + i * 2 + 1] + d2 * xz[i * 2 + 1];
        float acc = bz[j] + t0 * Wz[j] + t1 * Wz[HID + j];
        out[t] = fmaxf(acc, 0.0f);
    } else if (t < TO) {
        int u = t - TZ;
        int i = u >> 6, j = u & 63;
        float di = ws[WS_DEG_O + i], d2 = di * di;
        float t0 = ws[WS_S_O + i * 3 + 0] + d2 * xo[i * 3 + 0];
        float t1 = ws[WS_S_O + i * 3 + 1] + d2 * xo[i * 3 + 1];
        float t2 = ws[WS_S_O + i * 3 + 2] + d2 * xo[i * 3 + 2];
        float acc = bo[j] + t0 * Wo[j] + t1 * Wo[HID + j] + t2 * Wo[2 * HID + j];
        out[t] = fmaxf(acc, 0.0f);
    } else if (t < TG) {
        int u = t - TO;
        int i = u >> 6, j = u & 63;
        float di = ws[WS_DEG_G + i], d2 = di * di;
        float t0 = ws[WS_S_G + i] + d2 * xg[i];
        float acc = bg[j] + t0 * Wg[j];
        out[t] = fmaxf(acc, 0.0f);
    }
}

extern "C" void kernel_launch(void* const* d_in, const int* in_sizes, int n_in,
                              void* d_out, int out_size, void* d_ws, size_t ws_size,
                              hipStream_t stream) {
    const float* xz = (const float*)d_in[0];
    const float* xo = (const float*)d_in[1];
    const float* xg = (const float*)d_in[2];
    const int*  eiz = (const int*)d_in[3];
    const int*  eio = (const int*)d_in[4];
    const int*  eig = (const int*)d_in[5];
    const float* Wz = (const float*)d_in[6];
    const float* Wo = (const float*)d_in[7];
    const float* Wg = (const float*)d_in[8];
    const float* bz = (const float*)d_in[9];
    const float* bo = (const float*)d_in[10];
    const float* bg = (const float*)d_in[11];
    const float* wz = (const float*)d_in[12];
    const float* wo = (const float*)d_in[13];
    const float* wg = (const float*)d_in[14];
    float* out = (float*)d_out;
    float* ws  = (float*)d_ws;

    const int B = 256;
    const int E_TOT = E_ZONE + E_OUT + E_GND;           // 4M
    const int OUT_TOT = (N_ZONE + N_OUT + N_GND) * HID; // 12.8M

    k_init<<<(WS_TOT + B - 1) / B, B, 0, stream>>>(ws);
    k_deg<<<(E_TOT + B - 1) / B, B, 0, stream>>>(eiz, wz, eio, wo, eig, wg, ws);
    k_dinv<<<(WS_DEG_TOT + B - 1) / B, B, 0, stream>>>(ws);
    k_scatter<<<(E_TOT + B - 1) / B, B, 0, stream>>>(eiz, wz, xz, eio, wo, xo, eig, wg, xg, ws);
    k_final<<<(OUT_TOT + B - 1) / B, B, 0, stream>>>(ws, xz, Wz, bz, xo, Wo, bo, xg, Wg, bg, out);
}

// Round 2
// 732.847 us; speedup vs baseline: 1.0282x; 1.0282x over previous
//
#include <hip/hip_runtime.h>

#define N_ZONE 100000
#define E_ZONE 2000000
#define N_OUT  50000
#define E_OUT  1000000
#define N_GND  50000
#define E_GND  1000000
#define HID    64

#define N_TOT   (N_ZONE + N_OUT + N_GND)   // 200000
#define NXCD    8

// ---------------- fast-path workspace layout (floats) ----------------
// per-XCD deg copies : 8 x 200000            [0, 1.6M)
// per-XCD s copies   : 8 x 450000            [1.6M, 5.2M)
//     per copy: s_zone 200000 (stride 2) | s_out 200000 (stride 4, ch3 pad) | s_gnd 50000
// dinv               : 200000               [5.2M, 5.4M)
// y = dinv*x packed  : 450000               [5.4M, 5.85M)  (zone f2 | out f4 pad | gnd f1)
// u = dinv*(sum s+y) : 450000               [5.85M, 6.3M)
#define OFF_DEGC 0
#define DEG_STRIDE 200000
#define OFF_SC   1600000
#define SC_STRIDE 450000
#define SC_Z     0
#define SC_O     200000
#define SC_G     400000
#define OFF_DINV 5200000
#define OFF_Y    5400000
#define Y_Z      0
#define Y_O      200000
#define Y_G      400000
#define OFF_U    5850000
#define FAST_WS_FLOATS 6300000
#define FAST_WS_BYTES  (FAST_WS_FLOATS * 4ull)
#define ZERO_FLOATS    5200000   // degc + sc regions

// physical XCD id: s_getreg hwreg(HW_REG_XCC_ID=20, offset 0, size 4)
// imm = (size-1)<<11 | offset<<6 | id = 3<<11 | 20 = 6164   [measured: learn_hip m09]
__device__ __forceinline__ int xcc8() {
    return (int)(__builtin_amdgcn_s_getreg(6164) & 7);
}

// workgroup-scope fadd on global memory: executes at the XCD's L2 (no sc1),
// atomic w.r.t. all blocks on the same XCD (L2 is that XCD's coherence point).
__device__ __forceinline__ void wgadd(float* p, float v) {
    __hip_atomic_fetch_add(p, v, __ATOMIC_RELAXED, __HIP_MEMORY_SCOPE_WORKGROUP);
}

// ---------------- fast path kernels ----------------

__global__ void k_deg(const int* __restrict__ eiz, const float* __restrict__ wz,
                      const int* __restrict__ eio, const float* __restrict__ wo,
                      const int* __restrict__ eig, const float* __restrict__ wg,
                      float* __restrict__ ws) {
    int t = blockIdx.x * blockDim.x + threadIdx.x;
    float* deg = ws + OFF_DEGC + xcc8() * DEG_STRIDE;
    if (t < E_ZONE) {
        wgadd(deg + eiz[E_ZONE + t], wz[t]);
    } else if (t < E_ZONE + E_OUT) {
        int e = t - E_ZONE;
        wgadd(deg + N_ZONE + eio[E_OUT + e], wo[e]);
    } else if (t < E_ZONE + E_OUT + E_GND) {
        int e = t - E_ZONE - E_OUT;
        wgadd(deg + N_ZONE + N_OUT + eig[E_GND + e], wg[e]);
    }
}

// reduce deg copies -> dinv; y = dinv * x (packed)
__global__ void k_red1(const float* __restrict__ xz, const float* __restrict__ xo,
                       const float* __restrict__ xg, float* __restrict__ ws) {
    int i = blockIdx.x * blockDim.x + threadIdx.x;
    if (i >= N_TOT) return;
    float d = 1.0f;  // self-loop weight
#pragma unroll
    for (int c = 0; c < NXCD; c++) d += ws[OFF_DEGC + c * DEG_STRIDE + i];
    float di = rsqrtf(d);
    ws[OFF_DINV + i] = di;
    if (i < N_ZONE) {
        ws[OFF_Y + Y_Z + 2 * i]     = di * xz[2 * i];
        ws[OFF_Y + Y_Z + 2 * i + 1] = di * xz[2 * i + 1];
    } else if (i < N_ZONE + N_OUT) {
        int u = i - N_ZONE;
        ws[OFF_Y + Y_O + 4 * u]     = di * xo[3 * u];
        ws[OFF_Y + Y_O + 4 * u + 1] = di * xo[3 * u + 1];
        ws[OFF_Y + Y_O + 4 * u + 2] = di * xo[3 * u + 2];
        ws[OFF_Y + Y_O + 4 * u + 3] = 0.0f;
    } else {
        int u = i - N_ZONE - N_OUT;
        ws[OFF_Y + Y_G + u] = di * xg[u];
    }
}

// s_c[col][k] += w * y[row][k]  into this XCD's private copy
__global__ void k_scat(const int* __restrict__ eiz, const float* __restrict__ wz,
                       const int* __restrict__ eio, const float* __restrict__ wo,
                       const int* __restrict__ eig, const float* __restrict__ wg,
                       float* __restrict__ ws) {
    int t = blockIdx.x * blockDim.x + threadIdx.x;
    float* sc = ws + OFF_SC + xcc8() * SC_STRIDE;
    const float* y = ws + OFF_Y;
    if (t < E_ZONE) {
        int row = eiz[t], col = eiz[E_ZONE + t];
        float w = wz[t];
        wgadd(sc + SC_Z + 2 * col,     w * y[Y_Z + 2 * row]);
        wgadd(sc + SC_Z + 2 * col + 1, w * y[Y_Z + 2 * row + 1]);
    } else if (t < E_ZONE + E_OUT) {
        int e = t - E_ZONE;
        int row = eio[e], col = eio[E_OUT + e];
        float w = wo[e];
        wgadd(sc + SC_O + 4 * col,     w * y[Y_O + 4 * row]);
        wgadd(sc + SC_O + 4 * col + 1, w * y[Y_O + 4 * row + 1]);
        wgadd(sc + SC_O + 4 * col + 2, w * y[Y_O + 4 * row + 2]);
    } else if (t < E_ZONE + E_OUT + E_GND) {
        int e = t - E_ZONE - E_OUT;
        int row = eig[e], col = eig[E_GND + e];
        wgadd(sc + SC_G + col, wg[e] * y[Y_G + row]);
    }
}

// u[p] = dinv[node(p)] * (sum_c s_c[p] + y[p])
__global__ void k_red2(float* __restrict__ ws) {
    int p = blockIdx.x * blockDim.x + threadIdx.x;
    if (p >= SC_STRIDE) return;
    float s = ws[OFF_Y + p];
#pragma unroll
    for (int c = 0; c < NXCD; c++) s += ws[OFF_SC + c * SC_STRIDE + p];
    int i;
    if (p < SC_O)      i = p >> 1;
    else if (p < SC_G) i = N_ZONE + ((p - SC_O) >> 2);
    else               i = N_ZONE + N_OUT + (p - SC_G);
    ws[OFF_U + p] = ws[OFF_DINV + i] * s;
}

// out = relu(u @ W + b)
__global__ void k_fin(const float* __restrict__ ws,
                      const float* __restrict__ Wz, const float* __restrict__ bz,
                      const float* __restrict__ Wo, const float* __restrict__ bo,
                      const float* __restrict__ Wg, const float* __restrict__ bg,
                      float* __restrict__ out) {
    int t = blockIdx.x * blockDim.x + threadIdx.x;
    const int TZ = N_ZONE * HID;
    const int TO = TZ + N_OUT * HID;
    const int TG = TO + N_GND * HID;
    if (t < TZ) {
        int i = t >> 6, j = t & 63;
        float u0 = ws[OFF_U + 2 * i], u1 = ws[OFF_U + 2 * i + 1];
        out[t] = fmaxf(bz[j] + u0 * Wz[j] + u1 * Wz[HID + j], 0.0f);
    } else if (t < TO) {
        int q = t - TZ;
        int i = q >> 6, j = q & 63;
        const float* u = ws + OFF_U + SC_O + 4 * i;
        out[t] = fmaxf(bo[j] + u[0] * Wo[j] + u[1] * Wo[HID + j] + u[2] * Wo[2 * HID + j], 0.0f);
    } else if (t < TG) {
        int q = t - TO;
        int i = q >> 6, j = q & 63;
        out[t] = fmaxf(bg[j] + ws[OFF_U + SC_G + i] * Wg[j], 0.0f);
    }
}

// ---------------- fallback path (proven R1 kernels, 2.4 MB ws) ----------------
#define F_DEG_Z   0
#define F_DEG_O   (N_ZONE)
#define F_DEG_G   (N_ZONE + N_OUT)
#define F_DEG_TOT N_TOT
#define F_S_Z     F_DEG_TOT
#define F_S_O     (F_S_Z + N_ZONE * 2)
#define F_S_G     (F_S_O + N_OUT * 3)
#define F_TOT     (F_S_G + N_GND * 1)

__global__ void f_init(float* __restrict__ ws) {
    int i = blockIdx.x * blockDim.x + threadIdx.x;
    if (i < F_TOT) ws[i] = (i < F_DEG_TOT) ? 1.0f : 0.0f;
}
__global__ void f_deg(const int* __restrict__ eiz, const float* __restrict__ wz,
                      const int* __restrict__ eio, const float* __restrict__ wo,
                      const int* __restrict__ eig, const float* __restrict__ wg,
                      float* __restrict__ ws) {
    int t = blockIdx.x * blockDim.x + threadIdx.x;
    if (t < E_ZONE) atomicAdd(ws + F_DEG_Z + eiz[E_ZONE + t], wz[t]);
    else if (t < E_ZONE + E_OUT) { int e = t - E_ZONE; atomicAdd(ws + F_DEG_O + eio[E_OUT + e], wo[e]); }
    else if (t < E_ZONE + E_OUT + E_GND) { int e = t - E_ZONE - E_OUT; atomicAdd(ws + F_DEG_G + eig[E_GND + e], wg[e]); }
}
__global__ void f_dinv(float* __restrict__ ws) {
    int i = blockIdx.x * blockDim.x + threadIdx.x;
    if (i < F_DEG_TOT) ws[i] = 1.0f / sqrtf(ws[i]);
}
__global__ void f_scatter(const int* __restrict__ eiz, const float* __restrict__ wz, const float* __restrict__ xz,
                          const int* __restrict__ eio, const float* __restrict__ wo, const float* __restrict__ xo,
                          const int* __restrict__ eig, const float* __restrict__ wg, const float* __restrict__ xg,
                          float* __restrict__ ws) {
    int t = blockIdx.x * blockDim.x + threadIdx.x;
    if (t < E_ZONE) {
        int row = eiz[t], col = eiz[E_ZONE + t];
        float n = ws[F_DEG_Z + row] * wz[t] * ws[F_DEG_Z + col];
        atomicAdd(ws + F_S_Z + col * 2 + 0, n * xz[row * 2 + 0]);
        atomicAdd(ws + F_S_Z + col * 2 + 1, n * xz[row * 2 + 1]);
    } else if (t < E_ZONE + E_OUT) {
        int e = t - E_ZONE;
        int row = eio[e], col = eio[E_OUT + e];
        float n = ws[F_DEG_O + row] * wo[e] * ws[F_DEG_O + col];
        atomicAdd(ws + F_S_O + col * 3 + 0, n * xo[row * 3 + 0]);
        atomicAdd(ws + F_S_O + col * 3 + 1, n * xo[row * 3 + 1]);
        atomicAdd(ws + F_S_O + col * 3 + 2, n * xo[row * 3 + 2]);
    } else if (t < E_ZONE + E_OUT + E_GND) {
        int e = t - E_ZONE - E_OUT;
        int row = eig[e], col = eig[E_GND + e];
        float n = ws[F_DEG_G + row] * wg[e] * ws[F_DEG_G + col];
        atomicAdd(ws + F_S_G + col, n * xg[row]);
    }
}
__global__ void f_final(const float* __restrict__ ws,
                        const float* __restrict__ xz, const float* __restrict__ Wz, const float* __restrict__ bz,
                        const float* __restrict__ xo, const float* __restrict__ Wo, const float* __restrict__ bo,
                        const float* __restrict__ xg, const float* __restrict__ Wg, const float* __restrict__ bg,
                        float* __restrict__ out) {
    int t = blockIdx.x * blockDim.x + threadIdx.x;
    const int TZ = N_ZONE * HID;
    const int TO = TZ + N_OUT * HID;
    const int TG = TO + N_GND * HID;
    if (t < TZ) {
        int i = t >> 6, j = t & 63;
        float di = ws[F_DEG_Z + i], d2 = di * di;
        float t0 = ws[F_S_Z + i * 2 + 0] + d2 * xz[i * 2 + 0];
        float t1 = ws[F_S_Z + i * 2 + 1] + d2 * xz[i * 2 + 1];
        out[t] = fmaxf(bz[j] + t0 * Wz[j] + t1 * Wz[HID + j], 0.0f);
    } else if (t < TO) {
        int u = t - TZ;
        int i = u >> 6, j = u & 63;
        float di = ws[F_DEG_O + i], d2 = di * di;
        float t0 = ws[F_S_O + i * 3 + 0] + d2 * xo[i * 3 + 0];
        float t1 = ws[F_S_O + i * 3 + 1] + d2 * xo[i * 3 + 1];
        float t2 = ws[F_S_O + i * 3 + 2] + d2 * xo[i * 3 + 2];
        out[t] = fmaxf(bo[j] + t0 * Wo[j] + t1 * Wo[HID + j] + t2 * Wo[2 * HID + j], 0.0f);
    } else if (t < TG) {
        int u = t - TO;
        int i = u >> 6, j = u & 63;
        float di = ws[F_DEG_G + i], d2 = di * di;
        float t0 = ws[F_S_G + i] + d2 * xg[i];
        out[t] = fmaxf(bg[j] + t0 * Wg[j], 0.0f);
    }
}

extern "C" void kernel_launch(void* const* d_in, const int* in_sizes, int n_in,
                              void* d_out, int out_size, void* d_ws, size_t ws_size,
                              hipStream_t stream) {
    const float* xz = (const float*)d_in[0];
    const float* xo = (const float*)d_in[1];
    const float* xg = (const float*)d_in[2];
    const int*  eiz = (const int*)d_in[3];
    const int*  eio = (const int*)d_in[4];
    const int*  eig = (const int*)d_in[5];
    const float* Wz = (const float*)d_in[6];
    const float* Wo = (const float*)d_in[7];
    const float* Wg = (const float*)d_in[8];
    const float* bz = (const float*)d_in[9];
    const float* bo = (const float*)d_in[10];
    const float* bg = (const float*)d_in[11];
    const float* wz = (const float*)d_in[12];
    const float* wo = (const float*)d_in[13];
    const float* wg = (const float*)d_in[14];
    float* out = (float*)d_out;
    float* ws  = (float*)d_ws;

    const int B = 256;
    const int E_TOT = E_ZONE + E_OUT + E_GND;            // 4M
    const int OUT_TOT = N_TOT * HID;                     // 12.8M

    if (ws_size >= FAST_WS_BYTES) {
        hipMemsetAsync(ws, 0, ZERO_FLOATS * 4ull, stream);
        k_deg <<<(E_TOT + B - 1) / B, B, 0, stream>>>(eiz, wz, eio, wo, eig, wg, ws);
        k_red1<<<(N_TOT + B - 1) / B, B, 0, stream>>>(xz, xo, xg, ws);
        k_scat<<<(E_TOT + B - 1) / B, B, 0, stream>>>(eiz, wz, eio, wo, eig, wg, ws);
        k_red2<<<(SC_STRIDE + B - 1) / B, B, 0, stream>>>(ws);
        k_fin <<<(OUT_TOT + B - 1) / B, B, 0, stream>>>(ws, Wz, bz, Wo, bo, Wg, bg, out);
    } else {
        f_init<<<(F_TOT + B - 1) / B, B, 0, stream>>>(ws);
        f_deg<<<(E_TOT + B - 1) / B, B, 0, stream>>>(eiz, wz, eio, wo, eig, wg, ws);
        f_dinv<<<(F_DEG_TOT + B - 1) / B, B, 0, stream>>>(ws);
        f_scatter<<<(E_TOT + B - 1) / B, B, 0, stream>>>(eiz, wz, xz, eio, wo, xo, eig, wg, xg, ws);
        f_final<<<(OUT_TOT + B - 1) / B, B, 0, stream>>>(ws, xz, Wz, bz, xo, Wo, bo, xg, Wg, bg, out);
    }
}

// Round 3
// 307.268 us; speedup vs baseline: 2.4524x; 2.3850x over previous
//
#include <hip/hip_runtime.h>

#define N_ZONE 100000
#define E_ZONE 2000000
#define N_OUT  50000
#define E_OUT  1000000
#define N_GND  50000
#define E_GND  1000000
#define HID    64
#define N_TOT   (N_ZONE + N_OUT + N_GND)     // 200000
#define E_TOTAL (E_ZONE + E_OUT + E_GND)     // 4000000

// ---- binning geometry ----
#define RANGE   4096
#define RSHIFT  12
#define NBZ     25              // ceil(100000/4096)
#define NBO     13              // ceil(50000/4096)
#define NBG     13
#define NBUCKET (NBZ + NBO + NBG)            // 51
#define SLICES  8
#define OUT_PAD_BASE (NBZ * RANGE)           // 102400
#define GND_PAD_BASE ((NBZ + NBO) * RANGE)   // 155648
#define PAD_TOT      (NBUCKET * RANGE)       // 208896

// ---- workspace layout (f32 words) ----
#define WREC  0                               // uint2 records: ((colr<<17)|row, w)
#define WCTR  (2 * E_TOTAL)                   // u32 CNT[64] | CUR[64] | BASE[64]
#define WPDEG (WCTR + 256)
#define WPSZ  (WPDEG + NBUCKET * SLICES * RANGE)
#define WPSO  (WPSZ + NBZ * SLICES * RANGE * 2)
#define WPSG  (WPSO + NBO * SLICES * RANGE * 3)
#define WDINV (WPSG + NBG * SLICES * RANGE)
#define WYZ   (WDINV + PAD_TOT)
#define WYO   (WYZ + 2 * N_ZONE)
#define WYG   (WYO + 4 * N_OUT)
#define WUZ   (WYG + N_GND)
#define WUO   (WUZ + 2 * N_ZONE)
#define WUG   (WUO + 4 * N_OUT)
#define WTOT  (WUG + N_GND)
#define FAST_WS_BYTES ((size_t)WTOT * 4)

#define CNT_CHUNK 16384
#define BIN_CHUNK 4096

// K1: per-block histogram of destination buckets -> global CNT
__global__ void k_count(const int* __restrict__ eiz, const int* __restrict__ eio,
                        const int* __restrict__ eig, unsigned* __restrict__ cnt) {
    __shared__ unsigned hist[NBUCKET];
    int tid = threadIdx.x;
    for (int b = tid; b < NBUCKET; b += 256) hist[b] = 0;
    __syncthreads();
    int t0 = blockIdx.x * CNT_CHUNK;
#pragma unroll 4
    for (int i = 0; i < CNT_CHUNK / 256; i++) {
        int t = t0 + i * 256 + tid;
        if (t < E_TOTAL) {
            int b;
            if (t < E_ZONE) b = eiz[E_ZONE + t] >> RSHIFT;
            else if (t < E_ZONE + E_OUT) b = NBZ + (eio[E_OUT + (t - E_ZONE)] >> RSHIFT);
            else b = NBZ + NBO + (eig[E_GND + (t - E_ZONE - E_OUT)] >> RSHIFT);
            atomicAdd(&hist[b], 1u);
        }
    }
    __syncthreads();
    for (int b = tid; b < NBUCKET; b += 256)
        if (hist[b]) atomicAdd(&cnt[b], hist[b]);
}

// K2: exclusive scan of CNT -> BASE, init CUR
__global__ void k_scan(unsigned* __restrict__ ctr) {
    if (threadIdx.x == 0) {
        unsigned acc = 0;
        for (int b = 0; b < NBUCKET; b++) {
            ctr[128 + b] = acc;      // BASE
            ctr[64 + b] = acc;       // CUR
            acc += ctr[b];           // CNT
        }
    }
}

// K3: bin edges into bucket-contiguous records (LDS-staged for coalesced writes)
__global__ void k_bin(const int* __restrict__ eiz, const float* __restrict__ wz,
                      const int* __restrict__ eio, const float* __restrict__ wo,
                      const int* __restrict__ eig, const float* __restrict__ wg,
                      unsigned* __restrict__ ctr, uint2* __restrict__ rec) {
    __shared__ unsigned lds_a[BIN_CHUNK];
    __shared__ float    lds_w[BIN_CHUNK];
    __shared__ unsigned hist[NBUCKET];
    __shared__ unsigned sbase[NBUCKET];
    __shared__ unsigned gbase[NBUCKET];
    unsigned* cur = ctr + 64;
    int tid = threadIdx.x;
    for (int b = tid; b < NBUCKET; b += 256) hist[b] = 0;
    __syncthreads();
    int t0 = blockIdx.x * BIN_CHUNK;
    unsigned mya[BIN_CHUNK / 256], myb[BIN_CHUNK / 256], myr[BIN_CHUNK / 256];
    float myw[BIN_CHUNK / 256];
#pragma unroll
    for (int i = 0; i < BIN_CHUNK / 256; i++) {
        int t = t0 + i * 256 + tid;
        unsigned b = 0xFFFFFFFFu;
        if (t < E_TOTAL) {
            int row, col; float w;
            if (t < E_ZONE) { row = eiz[t]; col = eiz[E_ZONE + t]; w = wz[t]; b = col >> RSHIFT; }
            else if (t < E_ZONE + E_OUT) { int e = t - E_ZONE; row = eio[e]; col = eio[E_OUT + e]; w = wo[e]; b = NBZ + (col >> RSHIFT); }
            else { int e = t - E_ZONE - E_OUT; row = eig[e]; col = eig[E_GND + e]; w = wg[e]; b = NBZ + NBO + (col >> RSHIFT); }
            mya[i] = ((unsigned)(col & (RANGE - 1)) << 17) | (unsigned)row;
            myw[i] = w;
            myr[i] = atomicAdd(&hist[b], 1u);
        }
        myb[i] = b;
    }
    __syncthreads();
    if (tid == 0) {
        unsigned acc = 0;
        for (int b = 0; b < NBUCKET; b++) { sbase[b] = acc; acc += hist[b]; }
    }
    __syncthreads();
    for (int b = tid; b < NBUCKET; b += 256)
        gbase[b] = hist[b] ? atomicAdd(&cur[b], hist[b]) : 0u;
#pragma unroll
    for (int i = 0; i < BIN_CHUNK / 256; i++) {
        if (myb[i] < NBUCKET) {
            unsigned p = sbase[myb[i]] + myr[i];
            lds_a[p] = mya[i];
            lds_w[p] = myw[i];
        }
    }
    __syncthreads();
    for (int b = 0; b < NBUCKET; b++) {
        unsigned c = hist[b], gb = gbase[b], sb = sbase[b];
        for (unsigned j = tid; j < c; j += 256)
            rec[gb + j] = make_uint2(lds_a[sb + j], __float_as_uint(lds_w[sb + j]));
    }
}

// K4: per (range, slice): LDS-accumulate deg, write dense partial
__global__ void k_degp(const uint2* __restrict__ rec, const unsigned* __restrict__ ctr,
                       float* __restrict__ pdeg) {
    __shared__ float deg[RANGE];
    int r = blockIdx.x >> 3, sl = blockIdx.x & 7, tid = threadIdx.x;
    for (int i = tid; i < RANGE; i += 256) deg[i] = 0.0f;
    __syncthreads();
    unsigned c = ctr[r], b0 = ctr[128 + r];
    unsigned per = (c + SLICES - 1) / SLICES;
    unsigned s0 = sl * per;
    unsigned s1 = s0 + per; if (s1 > c) s1 = c;
    for (unsigned j = s0 + tid; j < s1; j += 256) {
        uint2 q = rec[b0 + j];
        atomicAdd(&deg[q.x >> 17], __uint_as_float(q.y));
    }
    __syncthreads();
    float* o = pdeg + (size_t)blockIdx.x * RANGE;
    for (int i = tid; i < RANGE; i += 256) o[i] = deg[i];
}

// K5: reduce deg partials -> dinv (padded space); y = dinv * x (graph-local)
__global__ void k_dinvy(const float* __restrict__ xz, const float* __restrict__ xo,
                        const float* __restrict__ xg, float* __restrict__ ws) {
    int p = blockIdx.x * blockDim.x + threadIdx.x;
    if (p >= PAD_TOT) return;
    int r = p >> RSHIFT, i = p & (RANGE - 1);
    float d = 1.0f;
#pragma unroll
    for (int sl = 0; sl < SLICES; sl++)
        d += ws[WPDEG + (size_t)(r * SLICES + sl) * RANGE + i];
    float di = rsqrtf(d);
    ws[WDINV + p] = di;
    if (p < OUT_PAD_BASE) {
        if (p < N_ZONE) {
            ws[WYZ + 2 * p]     = di * xz[2 * p];
            ws[WYZ + 2 * p + 1] = di * xz[2 * p + 1];
        }
    } else if (p < GND_PAD_BASE) {
        int idx = p - OUT_PAD_BASE;
        if (idx < N_OUT) {
            ws[WYO + 4 * idx]     = di * xo[3 * idx];
            ws[WYO + 4 * idx + 1] = di * xo[3 * idx + 1];
            ws[WYO + 4 * idx + 2] = di * xo[3 * idx + 2];
            ws[WYO + 4 * idx + 3] = 0.0f;
        }
    } else {
        int idx = p - GND_PAD_BASE;
        if (idx < N_GND) ws[WYG + idx] = di * xg[idx];
    }
}

// K6: per (range, slice): LDS-accumulate s[col][ch] += w*y[row][ch], write partial
__global__ void k_sp(float* __restrict__ ws) {
    __shared__ float s[RANGE * 3];
    int r = blockIdx.x >> 3, sl = blockIdx.x & 7, tid = threadIdx.x;
    const unsigned* ctr = (const unsigned*)(ws + WCTR);
    const uint2* rec = (const uint2*)ws;
    int ch, rg; size_t ybase, psbase;
    if (r < NBZ)            { ch = 2; rg = r;             ybase = WYZ; psbase = WPSZ; }
    else if (r < NBZ + NBO) { ch = 3; rg = r - NBZ;       ybase = WYO; psbase = WPSO; }
    else                    { ch = 1; rg = r - NBZ - NBO; ybase = WYG; psbase = WPSG; }
    int tot = RANGE * ch;
    for (int i = tid; i < tot; i += 256) s[i] = 0.0f;
    __syncthreads();
    unsigned c = ctr[r], b0 = ctr[128 + r];
    unsigned per = (c + SLICES - 1) / SLICES;
    unsigned s0 = sl * per;
    unsigned s1 = s0 + per; if (s1 > c) s1 = c;
    if (ch == 2) {
        const float2* y = (const float2*)(ws + ybase);
        for (unsigned j = s0 + tid; j < s1; j += 256) {
            uint2 q = rec[b0 + j];
            unsigned colr = q.x >> 17, row = q.x & 0x1FFFFu;
            float w = __uint_as_float(q.y);
            float2 yv = y[row];
            atomicAdd(&s[colr * 2],     w * yv.x);
            atomicAdd(&s[colr * 2 + 1], w * yv.y);
        }
    } else if (ch == 3) {
        const float4* y = (const float4*)(ws + ybase);
        for (unsigned j = s0 + tid; j < s1; j += 256) {
            uint2 q = rec[b0 + j];
            unsigned colr = q.x >> 17, row = q.x & 0x1FFFFu;
            float w = __uint_as_float(q.y);
            float4 yv = y[row];
            atomicAdd(&s[colr * 3],     w * yv.x);
            atomicAdd(&s[colr * 3 + 1], w * yv.y);
            atomicAdd(&s[colr * 3 + 2], w * yv.z);
        }
    } else {
        const float* y = ws + ybase;
        for (unsigned j = s0 + tid; j < s1; j += 256) {
            uint2 q = rec[b0 + j];
            atomicAdd(&s[q.x >> 17], __uint_as_float(q.y) * y[q.x & 0x1FFFFu]);
        }
    }
    __syncthreads();
    float* o = ws + psbase + (size_t)(rg * SLICES + sl) * tot;
    for (int i = tid; i < tot; i += 256) o[i] = s[i];
}

// K7: u = dinv * (y + sum_slices partial_s)
__global__ void k_u(float* __restrict__ ws) {
    int p = blockIdx.x * blockDim.x + threadIdx.x;
    if (p >= PAD_TOT) return;
    int r = p >> RSHIFT, i = p & (RANGE - 1);
    float di = ws[WDINV + p];
    if (p < OUT_PAD_BASE) {
        if (p >= N_ZONE) return;
        float s0 = ws[WYZ + 2 * p], s1 = ws[WYZ + 2 * p + 1];
#pragma unroll
        for (int sl = 0; sl < SLICES; sl++) {
            const float* ps = ws + WPSZ + (size_t)(r * SLICES + sl) * RANGE * 2;
            s0 += ps[2 * i]; s1 += ps[2 * i + 1];
        }
        ws[WUZ + 2 * p] = di * s0; ws[WUZ + 2 * p + 1] = di * s1;
    } else if (p < GND_PAD_BASE) {
        int idx = p - OUT_PAD_BASE;
        if (idx >= N_OUT) return;
        int rg = r - NBZ;
        float s0 = ws[WYO + 4 * idx], s1 = ws[WYO + 4 * idx + 1], s2 = ws[WYO + 4 * idx + 2];
#pragma unroll
        for (int sl = 0; sl < SLICES; sl++) {
            const float* ps = ws + WPSO + (size_t)(rg * SLICES + sl) * RANGE * 3;
            s0 += ps[3 * i]; s1 += ps[3 * i + 1]; s2 += ps[3 * i + 2];
        }
        ws[WUO + 4 * idx] = di * s0; ws[WUO + 4 * idx + 1] = di * s1; ws[WUO + 4 * idx + 2] = di * s2;
    } else {
        int idx = p - GND_PAD_BASE;
        if (idx >= N_GND) return;
        int rg = r - NBZ - NBO;
        float s0 = ws[WYG + idx];
#pragma unroll
        for (int sl = 0; sl < SLICES; sl++)
            s0 += ws[WPSG + (size_t)(rg * SLICES + sl) * RANGE + i];
        ws[WUG + idx] = di * s0;
    }
}

// K8: out = relu(u @ W + b)
__global__ void k_fin2(const float* __restrict__ ws,
                       const float* __restrict__ Wz, const float* __restrict__ bz,
                       const float* __restrict__ Wo, const float* __restrict__ bo,
                       const float* __restrict__ Wg, const float* __restrict__ bg,
                       float* __restrict__ out) {
    int t = blockIdx.x * blockDim.x + threadIdx.x;
    const int TZ = N_ZONE * HID, TO = TZ + N_OUT * HID, TG = TO + N_GND * HID;
    if (t < TZ) {
        int i = t >> 6, j = t & 63;
        float u0 = ws[WUZ + 2 * i], u1 = ws[WUZ + 2 * i + 1];
        out[t] = fmaxf(bz[j] + u0 * Wz[j] + u1 * Wz[HID + j], 0.0f);
    } else if (t < TO) {
        int q = t - TZ;
        int i = q >> 6, j = q & 63;
        const float* u = ws + WUO + 4 * i;
        out[t] = fmaxf(bo[j] + u[0] * Wo[j] + u[1] * Wo[HID + j] + u[2] * Wo[2 * HID + j], 0.0f);
    } else if (t < TG) {
        int q = t - TO;
        int i = q >> 6, j = q & 63;
        out[t] = fmaxf(bg[j] + ws[WUG + i] * Wg[j], 0.0f);
    }
}

// ---------------- fallback path (proven R1 kernels, 2.4 MB ws) ----------------
#define F_DEG_Z   0
#define F_DEG_O   (N_ZONE)
#define F_DEG_G   (N_ZONE + N_OUT)
#define F_DEG_TOT N_TOT
#define F_S_Z     F_DEG_TOT
#define F_S_O     (F_S_Z + N_ZONE * 2)
#define F_S_G     (F_S_O + N_OUT * 3)
#define F_TOT     (F_S_G + N_GND * 1)

__global__ void f_init(float* __restrict__ ws) {
    int i = blockIdx.x * blockDim.x + threadIdx.x;
    if (i < F_TOT) ws[i] = (i < F_DEG_TOT) ? 1.0f : 0.0f;
}
__global__ void f_deg(const int* __restrict__ eiz, const float* __restrict__ wz,
                      const int* __restrict__ eio, const float* __restrict__ wo,
                      const int* __restrict__ eig, const float* __restrict__ wg,
                      float* __restrict__ ws) {
    int t = blockIdx.x * blockDim.x + threadIdx.x;
    if (t < E_ZONE) atomicAdd(ws + F_DEG_Z + eiz[E_ZONE + t], wz[t]);
    else if (t < E_ZONE + E_OUT) { int e = t - E_ZONE; atomicAdd(ws + F_DEG_O + eio[E_OUT + e], wo[e]); }
    else if (t < E_ZONE + E_OUT + E_GND) { int e = t - E_ZONE - E_OUT; atomicAdd(ws + F_DEG_G + eig[E_GND + e], wg[e]); }
}
__global__ void f_dinv(float* __restrict__ ws) {
    int i = blockIdx.x * blockDim.x + threadIdx.x;
    if (i < F_DEG_TOT) ws[i] = 1.0f / sqrtf(ws[i]);
}
__global__ void f_scatter(const int* __restrict__ eiz, const float* __restrict__ wz, const float* __restrict__ xz,
                          const int* __restrict__ eio, const float* __restrict__ wo, const float* __restrict__ xo,
                          const int* __restrict__ eig, const float* __restrict__ wg, const float* __restrict__ xg,
                          float* __restrict__ ws) {
    int t = blockIdx.x * blockDim.x + threadIdx.x;
    if (t < E_ZONE) {
        int row = eiz[t], col = eiz[E_ZONE + t];
        float n = ws[F_DEG_Z + row] * wz[t] * ws[F_DEG_Z + col];
        atomicAdd(ws + F_S_Z + col * 2 + 0, n * xz[row * 2 + 0]);
        atomicAdd(ws + F_S_Z + col * 2 + 1, n * xz[row * 2 + 1]);
    } else if (t < E_ZONE + E_OUT) {
        int e = t - E_ZONE;
        int row = eio[e], col = eio[E_OUT + e];
        float n = ws[F_DEG_O + row] * wo[e] * ws[F_DEG_O + col];
        atomicAdd(ws + F_S_O + col * 3 + 0, n * xo[row * 3 + 0]);
        atomicAdd(ws + F_S_O + col * 3 + 1, n * xo[row * 3 + 1]);
        atomicAdd(ws + F_S_O + col * 3 + 2, n * xo[row * 3 + 2]);
    } else if (t < E_ZONE + E_OUT + E_GND) {
        int e = t - E_ZONE - E_OUT;
        int row = eig[e], col = eig[E_GND + e];
        float n = ws[F_DEG_G + row] * wg[e] * ws[F_DEG_G + col];
        atomicAdd(ws + F_S_G + col, n * xg[row]);
    }
}
__global__ void f_final(const float* __restrict__ ws,
                        const float* __restrict__ xz, const float* __restrict__ Wz, const float* __restrict__ bz,
                        const float* __restrict__ xo, const float* __restrict__ Wo, const float* __restrict__ bo,
                        const float* __restrict__ xg, const float* __restrict__ Wg, const float* __restrict__ bg,
                        float* __restrict__ out) {
    int t = blockIdx.x * blockDim.x + threadIdx.x;
    const int TZ = N_ZONE * HID, TO = TZ + N_OUT * HID, TG = TO + N_GND * HID;
    if (t < TZ) {
        int i = t >> 6, j = t & 63;
        float di = ws[F_DEG_Z + i], d2 = di * di;
        float t0 = ws[F_S_Z + i * 2 + 0] + d2 * xz[i * 2 + 0];
        float t1 = ws[F_S_Z + i * 2 + 1] + d2 * xz[i * 2 + 1];
        out[t] = fmaxf(bz[j] + t0 * Wz[j] + t1 * Wz[HID + j], 0.0f);
    } else if (t < TO) {
        int u = t - TZ;
        int i = u >> 6, j = u & 63;
        float di = ws[F_DEG_O + i], d2 = di * di;
        float t0 = ws[F_S_O + i * 3 + 0] + d2 * xo[i * 3 + 0];
        float t1 = ws[F_S_O + i * 3 + 1] + d2 * xo[i * 3 + 1];
        float t2 = ws[F_S_O + i * 3 + 2] + d2 * xo[i * 3 + 2];
        out[t] = fmaxf(bo[j] + t0 * Wo[j] + t1 * Wo[HID + j] + t2 * Wo[2 * HID + j], 0.0f);
    } else if (t < TG) {
        int u = t - TO;
        int i = u >> 6, j = u & 63;
        float di = ws[F_DEG_G + i], d2 = di * di;
        float t0 = ws[F_S_G + i] + d2 * xg[i];
        out[t] = fmaxf(bg[j] + t0 * Wg[j], 0.0f);
    }
}

extern "C" void kernel_launch(void* const* d_in, const int* in_sizes, int n_in,
                              void* d_out, int out_size, void* d_ws, size_t ws_size,
                              hipStream_t stream) {
    const float* xz = (const float*)d_in[0];
    const float* xo = (const float*)d_in[1];
    const float* xg = (const float*)d_in[2];
    const int*  eiz = (const int*)d_in[3];
    const int*  eio = (const int*)d_in[4];
    const int*  eig = (const int*)d_in[5];
    const float* Wz = (const float*)d_in[6];
    const float* Wo = (const float*)d_in[7];
    const float* Wg = (const float*)d_in[8];
    const float* bz = (const float*)d_in[9];
    const float* bo = (const float*)d_in[10];
    const float* bg = (const float*)d_in[11];
    const float* wz = (const float*)d_in[12];
    const float* wo = (const float*)d_in[13];
    const float* wg = (const float*)d_in[14];
    float* out = (float*)d_out;
    float* ws  = (float*)d_ws;

    const int B = 256;

    if (ws_size >= FAST_WS_BYTES) {
        unsigned* ctr = (unsigned*)(ws + WCTR);
        uint2* rec = (uint2*)ws;
        hipMemsetAsync(ctr, 0, 256 * 4, stream);
        k_count<<<(E_TOTAL + CNT_CHUNK - 1) / CNT_CHUNK, B, 0, stream>>>(eiz, eio, eig, ctr);
        k_scan<<<1, 64, 0, stream>>>(ctr);
        k_bin<<<(E_TOTAL + BIN_CHUNK - 1) / BIN_CHUNK, B, 0, stream>>>(eiz, wz, eio, wo, eig, wg, ctr, rec);
        k_degp<<<NBUCKET * SLICES, B, 0, stream>>>(rec, ctr, ws + WPDEG);
        k_dinvy<<<(PAD_TOT + B - 1) / B, B, 0, stream>>>(xz, xo, xg, ws);
        k_sp<<<NBUCKET * SLICES, B, 0, stream>>>(ws);
        k_u<<<(PAD_TOT + B - 1) / B, B, 0, stream>>>(ws);
        k_fin2<<<(N_TOT * HID) / B, B, 0, stream>>>(ws, Wz, bz, Wo, bo, Wg, bg, out);
    } else {
        const int E_TOT = E_TOTAL, OUT_TOT = N_TOT * HID;
        f_init<<<(F_TOT + B - 1) / B, B, 0, stream>>>(ws);
        f_deg<<<(E_TOT + B - 1) / B, B, 0, stream>>>(eiz, wz, eio, wo, eig, wg, ws);
        f_dinv<<<(F_DEG_TOT + B - 1) / B, B, 0, stream>>>(ws);
        f_scatter<<<(E_TOT + B - 1) / B, B, 0, stream>>>(eiz, wz, xz, eio, wo, xo, eig, wg, xg, ws);
        f_final<<<(OUT_TOT + B - 1) / B, B, 0, stream>>>(ws, xz, Wz, bz, xo, Wo, bo, xg, Wg, bg, out);
    }
}

// Round 4
// 301.403 us; speedup vs baseline: 2.5001x; 1.0195x over previous
//
#include <hip/hip_runtime.h>

#define N_ZONE 100000
#define E_ZONE 2000000
#define N_OUT  50000
#define E_OUT  1000000
#define N_GND  50000
#define E_GND  1000000
#define HID    64
#define N_TOT   (N_ZONE + N_OUT + N_GND)     // 200000
#define E_TOTAL (E_ZONE + E_OUT + E_GND)     // 4000000

// ---- binning geometry ----
#define RANGE   2048
#define RSHIFT  11
#define NBZ     49              // ceil(100000/2048)
#define NBO     25              // ceil(50000/2048)
#define NBG     25
#define NBUCKET (NBZ + NBO + NBG)            // 99
#define SLICES  12
#define OUT_PAD_BASE (NBZ * RANGE)           // 100352
#define GND_PAD_BASE ((NBZ + NBO) * RANGE)   // 151552
#define PAD_TOT      (NBUCKET * RANGE)       // 202752

// ---- workspace layout (f32 words) ----
// rec | ctr | partials (deg overlaid by s: disjoint lifetimes) | dinv | y | u
#define WREC  0                               // uint2 rec: ((colr<<17)|row, w)
#define WCTR  (2 * E_TOTAL)                   // u32 CNT[128] | CUR[128] | BASE[128]
#define WPART (WCTR + 384)
#define WPDEG WPART                           // 99*12*2048        = 2433024
#define WPSZ  WPART                           // 49*12*2048*2      = 2408448
#define WPSO  (WPSZ + NBZ * SLICES * RANGE * 2)
#define WPSG  (WPSO + NBO * SLICES * RANGE * 3)
#define WPEND (WPSG + NBG * SLICES * RANGE)   // WPART + 4866048
#define WDINV WPEND
#define WYZ   (WDINV + PAD_TOT)
#define WYO   (WYZ + 2 * N_ZONE)
#define WYG   (WYO + 4 * N_OUT)
#define WUZ   (WYG + N_GND)
#define WUO   (WUZ + 2 * N_ZONE)
#define WUG   (WUO + 4 * N_OUT)
#define WTOT  (WUG + N_GND)                   // 13969184 fl = 55.88 MB (<= 56.49 proven)
#define FAST_WS_BYTES ((size_t)WTOT * 4)

#define CNT_CHUNK 16384
#define BIN_CHUNK 4096

// K1: per-block histogram of destination buckets -> global CNT
__global__ void k_count(const int* __restrict__ eiz, const int* __restrict__ eio,
                        const int* __restrict__ eig, unsigned* __restrict__ cnt) {
    __shared__ unsigned hist[NBUCKET];
    int tid = threadIdx.x;
    for (int b = tid; b < NBUCKET; b += 256) hist[b] = 0;
    __syncthreads();
    int t0 = blockIdx.x * CNT_CHUNK;
#pragma unroll 4
    for (int i = 0; i < CNT_CHUNK / 256; i++) {
        int t = t0 + i * 256 + tid;
        if (t < E_TOTAL) {
            int b;
            if (t < E_ZONE) b = eiz[E_ZONE + t] >> RSHIFT;
            else if (t < E_ZONE + E_OUT) b = NBZ + (eio[E_OUT + (t - E_ZONE)] >> RSHIFT);
            else b = NBZ + NBO + (eig[E_GND + (t - E_ZONE - E_OUT)] >> RSHIFT);
            atomicAdd(&hist[b], 1u);
        }
    }
    __syncthreads();
    for (int b = tid; b < NBUCKET; b += 256)
        if (hist[b]) atomicAdd(&cnt[b], hist[b]);
}

// K2: exclusive scan of CNT -> BASE (ctr+256), init CUR (ctr+128)
__global__ void k_scan(unsigned* __restrict__ ctr) {
    if (threadIdx.x == 0) {
        unsigned acc = 0;
        for (int b = 0; b < NBUCKET; b++) {
            ctr[256 + b] = acc;
            ctr[128 + b] = acc;
            acc += ctr[b];
        }
    }
}

// K3: bin edges into bucket-contiguous records (LDS-staged, wave-parallel copy-out)
__global__ void k_bin(const int* __restrict__ eiz, const float* __restrict__ wz,
                      const int* __restrict__ eio, const float* __restrict__ wo,
                      const int* __restrict__ eig, const float* __restrict__ wg,
                      unsigned* __restrict__ ctr, uint2* __restrict__ rec) {
    __shared__ unsigned lds_a[BIN_CHUNK];
    __shared__ float    lds_w[BIN_CHUNK];
    __shared__ unsigned hist[NBUCKET];
    __shared__ unsigned sbase[NBUCKET];
    __shared__ unsigned gbase[NBUCKET];
    unsigned* cur = ctr + 128;
    int tid = threadIdx.x;
    for (int b = tid; b < NBUCKET; b += 256) hist[b] = 0;
    __syncthreads();
    int t0 = blockIdx.x * BIN_CHUNK;
    unsigned mya[BIN_CHUNK / 256], myb[BIN_CHUNK / 256], myr[BIN_CHUNK / 256];
    float myw[BIN_CHUNK / 256];
#pragma unroll
    for (int i = 0; i < BIN_CHUNK / 256; i++) {
        int t = t0 + i * 256 + tid;
        unsigned b = 0xFFFFFFFFu;
        if (t < E_TOTAL) {
            int row, col; float w;
            if (t < E_ZONE) { row = eiz[t]; col = eiz[E_ZONE + t]; w = wz[t]; b = col >> RSHIFT; }
            else if (t < E_ZONE + E_OUT) { int e = t - E_ZONE; row = eio[e]; col = eio[E_OUT + e]; w = wo[e]; b = NBZ + (col >> RSHIFT); }
            else { int e = t - E_ZONE - E_OUT; row = eig[e]; col = eig[E_GND + e]; w = wg[e]; b = NBZ + NBO + (col >> RSHIFT); }
            mya[i] = ((unsigned)(col & (RANGE - 1)) << 17) | (unsigned)row;
            myw[i] = w;
            myr[i] = atomicAdd(&hist[b], 1u);
        }
        myb[i] = b;
    }
    __syncthreads();
    if (tid == 0) {
        unsigned acc = 0;
        for (int b = 0; b < NBUCKET; b++) { sbase[b] = acc; acc += hist[b]; }
    }
    __syncthreads();
    for (int b = tid; b < NBUCKET; b += 256)
        gbase[b] = hist[b] ? atomicAdd(&cur[b], hist[b]) : 0u;
#pragma unroll
    for (int i = 0; i < BIN_CHUNK / 256; i++) {
        if (myb[i] < NBUCKET) {
            unsigned p = sbase[myb[i]] + myr[i];
            lds_a[p] = mya[i];
            lds_w[p] = myw[i];
        }
    }
    __syncthreads();
    int wid = tid >> 6, lane = tid & 63;
    for (int b = wid; b < NBUCKET; b += 4) {
        unsigned c = hist[b], gb = gbase[b], sb = sbase[b];
        for (unsigned j = lane; j < c; j += 64)
            rec[gb + j] = make_uint2(lds_a[sb + j], __float_as_uint(lds_w[sb + j]));
    }
}

// K4: per (range, slice): LDS-accumulate deg, write dense partial
__global__ void k_degp(const uint2* __restrict__ rec, const unsigned* __restrict__ ctr,
                       float* __restrict__ pdeg) {
    __shared__ float deg[RANGE];
    int r = blockIdx.x / SLICES, sl = blockIdx.x % SLICES, tid = threadIdx.x;
    for (int i = tid; i < RANGE; i += 256) deg[i] = 0.0f;
    __syncthreads();
    unsigned c = ctr[r], b0 = ctr[256 + r];
    unsigned per = (c + SLICES - 1) / SLICES;
    unsigned s0 = sl * per;
    unsigned s1 = s0 + per; if (s1 > c) s1 = c;
    for (unsigned j = s0 + tid; j < s1; j += 256) {
        uint2 q = rec[b0 + j];
        atomicAdd(&deg[q.x >> 17], __uint_as_float(q.y));
    }
    __syncthreads();
    float* o = pdeg + (size_t)blockIdx.x * RANGE;
    for (int i = tid * 4; i < RANGE; i += 1024) {
        float4 v = *(float4*)&deg[i];
        *(float4*)&o[i] = v;
    }
}

// K5: reduce deg partials -> dinv (padded space); y = dinv * x (graph-local)
__global__ void k_dinvy(const float* __restrict__ xz, const float* __restrict__ xo,
                        const float* __restrict__ xg, float* __restrict__ ws) {
    int p = blockIdx.x * blockDim.x + threadIdx.x;
    if (p >= PAD_TOT) return;
    int r = p >> RSHIFT, i = p & (RANGE - 1);
    float d = 1.0f;
#pragma unroll
    for (int sl = 0; sl < SLICES; sl++)
        d += ws[WPDEG + (size_t)(r * SLICES + sl) * RANGE + i];
    float di = rsqrtf(d);
    ws[WDINV + p] = di;
    if (p < OUT_PAD_BASE) {
        if (p < N_ZONE) {
            ws[WYZ + 2 * p]     = di * xz[2 * p];
            ws[WYZ + 2 * p + 1] = di * xz[2 * p + 1];
        }
    } else if (p < GND_PAD_BASE) {
        int idx = p - OUT_PAD_BASE;
        if (idx < N_OUT) {
            ws[WYO + 4 * idx]     = di * xo[3 * idx];
            ws[WYO + 4 * idx + 1] = di * xo[3 * idx + 1];
            ws[WYO + 4 * idx + 2] = di * xo[3 * idx + 2];
            ws[WYO + 4 * idx + 3] = 0.0f;
        }
    } else {
        int idx = p - GND_PAD_BASE;
        if (idx < N_GND) ws[WYG + idx] = di * xg[idx];
    }
}

// K6: per (range, slice): LDS-accumulate s[col][ch] += w*y[row][ch], write partial.
// Template per graph so LDS is right-sized (zone 16KB, out 24KB, gnd 8KB).
template<int CH, int RSTART, int YOFF, int PSOFF>
__global__ void k_spT(float* __restrict__ ws) {
    __shared__ __align__(16) float s[RANGE * CH];
    int r = blockIdx.x / SLICES, sl = blockIdx.x % SLICES, tid = threadIdx.x;
    const unsigned* ctr = (const unsigned*)(ws + WCTR);
    const uint2* rec = (const uint2*)ws;
    const int tot = RANGE * CH;
    for (int i = tid; i < tot; i += 256) s[i] = 0.0f;
    __syncthreads();
    int rb = RSTART + r;
    unsigned c = ctr[rb], b0 = ctr[256 + rb];
    unsigned per = (c + SLICES - 1) / SLICES;
    unsigned s0 = sl * per;
    unsigned s1 = s0 + per; if (s1 > c) s1 = c;
    if constexpr (CH == 2) {
        const float2* y = (const float2*)(ws + YOFF);
        for (unsigned j = s0 + tid; j < s1; j += 256) {
            uint2 q = rec[b0 + j];
            unsigned colr = q.x >> 17, row = q.x & 0x1FFFFu;
            float w = __uint_as_float(q.y);
            float2 yv = y[row];
            atomicAdd(&s[colr * 2],     w * yv.x);
            atomicAdd(&s[colr * 2 + 1], w * yv.y);
        }
    } else if constexpr (CH == 3) {
        const float4* y = (const float4*)(ws + YOFF);
        for (unsigned j = s0 + tid; j < s1; j += 256) {
            uint2 q = rec[b0 + j];
            unsigned colr = q.x >> 17, row = q.x & 0x1FFFFu;
            float w = __uint_as_float(q.y);
            float4 yv = y[row];
            atomicAdd(&s[colr * 3],     w * yv.x);
            atomicAdd(&s[colr * 3 + 1], w * yv.y);
            atomicAdd(&s[colr * 3 + 2], w * yv.z);
        }
    } else {
        const float* y = ws + YOFF;
        for (unsigned j = s0 + tid; j < s1; j += 256) {
            uint2 q = rec[b0 + j];
            atomicAdd(&s[q.x >> 17], __uint_as_float(q.y) * y[q.x & 0x1FFFFu]);
        }
    }
    __syncthreads();
    float* o = ws + PSOFF + (size_t)(r * SLICES + sl) * tot;
    for (int i = tid * 4; i < tot; i += 1024) {
        float4 v = *(float4*)&s[i];
        *(float4*)&o[i] = v;
    }
}

// K7: u = dinv * (y + sum_slices partial_s)
__global__ void k_u(float* __restrict__ ws) {
    int p = blockIdx.x * blockDim.x + threadIdx.x;
    if (p >= PAD_TOT) return;
    int r = p >> RSHIFT, i = p & (RANGE - 1);
    float di = ws[WDINV + p];
    if (p < OUT_PAD_BASE) {
        if (p >= N_ZONE) return;
        float s0 = ws[WYZ + 2 * p], s1 = ws[WYZ + 2 * p + 1];
#pragma unroll
        for (int sl = 0; sl < SLICES; sl++) {
            const float* ps = ws + WPSZ + (size_t)(r * SLICES + sl) * RANGE * 2;
            s0 += ps[2 * i]; s1 += ps[2 * i + 1];
        }
        ws[WUZ + 2 * p] = di * s0; ws[WUZ + 2 * p + 1] = di * s1;
    } else if (p < GND_PAD_BASE) {
        int idx = p - OUT_PAD_BASE;
        if (idx >= N_OUT) return;
        int rg = r - NBZ;
        float s0 = ws[WYO + 4 * idx], s1 = ws[WYO + 4 * idx + 1], s2 = ws[WYO + 4 * idx + 2];
#pragma unroll
        for (int sl = 0; sl < SLICES; sl++) {
            const float* ps = ws + WPSO + (size_t)(rg * SLICES + sl) * RANGE * 3;
            s0 += ps[3 * i]; s1 += ps[3 * i + 1]; s2 += ps[3 * i + 2];
        }
        ws[WUO + 4 * idx] = di * s0; ws[WUO + 4 * idx + 1] = di * s1; ws[WUO + 4 * idx + 2] = di * s2;
    } else {
        int idx = p - GND_PAD_BASE;
        if (idx >= N_GND) return;
        int rg = r - NBZ - NBO;
        float s0 = ws[WYG + idx];
#pragma unroll
        for (int sl = 0; sl < SLICES; sl++)
            s0 += ws[WPSG + (size_t)(rg * SLICES + sl) * RANGE + i];
        ws[WUG + idx] = di * s0;
    }
}

// K8: out = relu(u @ W + b), 4 contiguous j per thread, float4 stores
__global__ void k_fin2(const float* __restrict__ ws,
                       const float* __restrict__ Wz, const float* __restrict__ bz,
                       const float* __restrict__ Wo, const float* __restrict__ bo,
                       const float* __restrict__ Wg, const float* __restrict__ bg,
                       float* __restrict__ out) {
    int t = blockIdx.x * blockDim.x + threadIdx.x;   // one per 4 outputs
    const int TZ4 = N_ZONE * 16, TO4 = TZ4 + N_OUT * 16, TG4 = TO4 + N_GND * 16;
    if (t < TZ4) {
        int i = t >> 4, jb = (t & 15) << 2;
        float u0 = ws[WUZ + 2 * i], u1 = ws[WUZ + 2 * i + 1];
        float4 w0 = *(const float4*)(Wz + jb);
        float4 w1 = *(const float4*)(Wz + HID + jb);
        float4 bv = *(const float4*)(bz + jb);
        float4 o;
        o.x = fmaxf(bv.x + u0 * w0.x + u1 * w1.x, 0.0f);
        o.y = fmaxf(bv.y + u0 * w0.y + u1 * w1.y, 0.0f);
        o.z = fmaxf(bv.z + u0 * w0.z + u1 * w1.z, 0.0f);
        o.w = fmaxf(bv.w + u0 * w0.w + u1 * w1.w, 0.0f);
        *(float4*)(out + i * HID + jb) = o;
    } else if (t < TO4) {
        int q = t - TZ4;
        int i = q >> 4, jb = (q & 15) << 2;
        const float* u = ws + WUO + 4 * i;
        float u0 = u[0], u1 = u[1], u2 = u[2];
        float4 w0 = *(const float4*)(Wo + jb);
        float4 w1 = *(const float4*)(Wo + HID + jb);
        float4 w2 = *(const float4*)(Wo + 2 * HID + jb);
        float4 bv = *(const float4*)(bo + jb);
        float4 o;
        o.x = fmaxf(bv.x + u0 * w0.x + u1 * w1.x + u2 * w2.x, 0.0f);
        o.y = fmaxf(bv.y + u0 * w0.y + u1 * w1.y + u2 * w2.y, 0.0f);
        o.z = fmaxf(bv.z + u0 * w0.z + u1 * w1.z + u2 * w2.z, 0.0f);
        o.w = fmaxf(bv.w + u0 * w0.w + u1 * w1.w + u2 * w2.w, 0.0f);
        *(float4*)(out + N_ZONE * HID + i * HID + jb) = o;
    } else if (t < TG4) {
        int q = t - TO4;
        int i = q >> 4, jb = (q & 15) << 2;
        float u0 = ws[WUG + i];
        float4 w0 = *(const float4*)(Wg + jb);
        float4 bv = *(const float4*)(bg + jb);
        float4 o;
        o.x = fmaxf(bv.x + u0 * w0.x, 0.0f);
        o.y = fmaxf(bv.y + u0 * w0.y, 0.0f);
        o.z = fmaxf(bv.z + u0 * w0.z, 0.0f);
        o.w = fmaxf(bv.w + u0 * w0.w, 0.0f);
        *(float4*)(out + (N_ZONE + N_OUT) * HID + i * HID + jb) = o;
    }
}

// ---------------- fallback path (proven R1 kernels, 2.4 MB ws) ----------------
#define F_DEG_Z   0
#define F_DEG_O   (N_ZONE)
#define F_DEG_G   (N_ZONE + N_OUT)
#define F_DEG_TOT N_TOT
#define F_S_Z     F_DEG_TOT
#define F_S_O     (F_S_Z + N_ZONE * 2)
#define F_S_G     (F_S_O + N_OUT * 3)
#define F_TOT     (F_S_G + N_GND * 1)

__global__ void f_init(float* __restrict__ ws) {
    int i = blockIdx.x * blockDim.x + threadIdx.x;
    if (i < F_TOT) ws[i] = (i < F_DEG_TOT) ? 1.0f : 0.0f;
}
__global__ void f_deg(const int* __restrict__ eiz, const float* __restrict__ wz,
                      const int* __restrict__ eio, const float* __restrict__ wo,
                      const int* __restrict__ eig, const float* __restrict__ wg,
                      float* __restrict__ ws) {
    int t = blockIdx.x * blockDim.x + threadIdx.x;
    if (t < E_ZONE) atomicAdd(ws + F_DEG_Z + eiz[E_ZONE + t], wz[t]);
    else if (t < E_ZONE + E_OUT) { int e = t - E_ZONE; atomicAdd(ws + F_DEG_O + eio[E_OUT + e], wo[e]); }
    else if (t < E_ZONE + E_OUT + E_GND) { int e = t - E_ZONE - E_OUT; atomicAdd(ws + F_DEG_G + eig[E_GND + e], wg[e]); }
}
__global__ void f_dinv(float* __restrict__ ws) {
    int i = blockIdx.x * blockDim.x + threadIdx.x;
    if (i < F_DEG_TOT) ws[i] = 1.0f / sqrtf(ws[i]);
}
__global__ void f_scatter(const int* __restrict__ eiz, const float* __restrict__ wz, const float* __restrict__ xz,
                          const int* __restrict__ eio, const float* __restrict__ wo, const float* __restrict__ xo,
                          const int* __restrict__ eig, const float* __restrict__ wg, const float* __restrict__ xg,
                          float* __restrict__ ws) {
    int t = blockIdx.x * blockDim.x + threadIdx.x;
    if (t < E_ZONE) {
        int row = eiz[t], col = eiz[E_ZONE + t];
        float n = ws[F_DEG_Z + row] * wz[t] * ws[F_DEG_Z + col];
        atomicAdd(ws + F_S_Z + col * 2 + 0, n * xz[row * 2 + 0]);
        atomicAdd(ws + F_S_Z + col * 2 + 1, n * xz[row * 2 + 1]);
    } else if (t < E_ZONE + E_OUT) {
        int e = t - E_ZONE;
        int row = eio[e], col = eio[E_OUT + e];
        float n = ws[F_DEG_O + row] * wo[e] * ws[F_DEG_O + col];
        atomicAdd(ws + F_S_O + col * 3 + 0, n * xo[row * 3 + 0]);
        atomicAdd(ws + F_S_O + col * 3 + 1, n * xo[row * 3 + 1]);
        atomicAdd(ws + F_S_O + col * 3 + 2, n * xo[row * 3 + 2]);
    } else if (t < E_ZONE + E_OUT + E_GND) {
        int e = t - E_ZONE - E_OUT;
        int row = eig[e], col = eig[E_GND + e];
        float n = ws[F_DEG_G + row] * wg[e] * ws[F_DEG_G + col];
        atomicAdd(ws + F_S_G + col, n * xg[row]);
    }
}
__global__ void f_final(const float* __restrict__ ws,
                        const float* __restrict__ xz, const float* __restrict__ Wz, const float* __restrict__ bz,
                        const float* __restrict__ xo, const float* __restrict__ Wo, const float* __restrict__ bo,
                        const float* __restrict__ xg, const float* __restrict__ Wg, const float* __restrict__ bg,
                        float* __restrict__ out) {
    int t = blockIdx.x * blockDim.x + threadIdx.x;
    const int TZ = N_ZONE * HID, TO = TZ + N_OUT * HID, TG = TO + N_GND * HID;
    if (t < TZ) {
        int i = t >> 6, j = t & 63;
        float di = ws[F_DEG_Z + i], d2 = di * di;
        float t0 = ws[F_S_Z + i * 2 + 0] + d2 * xz[i * 2 + 0];
        float t1 = ws[F_S_Z + i * 2 + 1] + d2 * xz[i * 2 + 1];
        out[t] = fmaxf(bz[j] + t0 * Wz[j] + t1 * Wz[HID + j], 0.0f);
    } else if (t < TO) {
        int u = t - TZ;
        int i = u >> 6, j = u & 63;
        float di = ws[F_DEG_O + i], d2 = di * di;
        float t0 = ws[F_S_O + i * 3 + 0] + d2 * xo[i * 3 + 0];
        float t1 = ws[F_S_O + i * 3 + 1] + d2 * xo[i * 3 + 1];
        float t2 = ws[F_S_O + i * 3 + 2] + d2 * xo[i * 3 + 2];
        out[t] = fmaxf(bo[j] + t0 * Wo[j] + t1 * Wo[HID + j] + t2 * Wo[2 * HID + j], 0.0f);
    } else if (t < TG) {
        int u = t - TO;
        int i = u >> 6, j = u & 63;
        float di = ws[F_DEG_G + i], d2 = di * di;
        float t0 = ws[F_S_G + i] + d2 * xg[i];
        out[t] = fmaxf(bg[j] + t0 * Wg[j], 0.0f);
    }
}

extern "C" void kernel_launch(void* const* d_in, const int* in_sizes, int n_in,
                              void* d_out, int out_size, void* d_ws, size_t ws_size,
                              hipStream_t stream) {
    const float* xz = (const float*)d_in[0];
    const float* xo = (const float*)d_in[1];
    const float* xg = (const float*)d_in[2];
    const int*  eiz = (const int*)d_in[3];
    const int*  eio = (const int*)d_in[4];
    const int*  eig = (const int*)d_in[5];
    const float* Wz = (const float*)d_in[6];
    const float* Wo = (const float*)d_in[7];
    const float* Wg = (const float*)d_in[8];
    const float* bz = (const float*)d_in[9];
    const float* bo = (const float*)d_in[10];
    const float* bg = (const float*)d_in[11];
    const float* wz = (const float*)d_in[12];
    const float* wo = (const float*)d_in[13];
    const float* wg = (const float*)d_in[14];
    float* out = (float*)d_out;
    float* ws  = (float*)d_ws;

    const int B = 256;

    if (ws_size >= FAST_WS_BYTES) {
        unsigned* ctr = (unsigned*)(ws + WCTR);
        uint2* rec = (uint2*)ws;
        hipMemsetAsync(ctr, 0, 384 * 4, stream);
        k_count<<<(E_TOTAL + CNT_CHUNK - 1) / CNT_CHUNK, B, 0, stream>>>(eiz, eio, eig, ctr);
        k_scan<<<1, 64, 0, stream>>>(ctr);
        k_bin<<<(E_TOTAL + BIN_CHUNK - 1) / BIN_CHUNK, B, 0, stream>>>(eiz, wz, eio, wo, eig, wg, ctr, rec);
        k_degp<<<NBUCKET * SLICES, B, 0, stream>>>(rec, ctr, ws + WPDEG);
        k_dinvy<<<(PAD_TOT + B - 1) / B, B, 0, stream>>>(xz, xo, xg, ws);
        k_spT<2, 0, WYZ, WPSZ><<<NBZ * SLICES, B, 0, stream>>>(ws);
        k_spT<3, NBZ, WYO, WPSO><<<NBO * SLICES, B, 0, stream>>>(ws);
        k_spT<1, NBZ + NBO, WYG, WPSG><<<NBG * SLICES, B, 0, stream>>>(ws);
        k_u<<<(PAD_TOT + B - 1) / B, B, 0, stream>>>(ws);
        k_fin2<<<(N_TOT * HID / 4 + B - 1) / B, B, 0, stream>>>(ws, Wz, bz, Wo, bo, Wg, bg, out);
    } else {
        const int E_TOT = E_TOTAL, OUT_TOT = N_TOT * HID;
        f_init<<<(F_TOT + B - 1) / B, B, 0, stream>>>(ws);
        f_deg<<<(E_TOT + B - 1) / B, B, 0, stream>>>(eiz, wz, eio, wo, eig, wg, ws);
        f_dinv<<<(F_DEG_TOT + B - 1) / B, B, 0, stream>>>(ws);
        f_scatter<<<(E_TOT + B - 1) / B, B, 0, stream>>>(eiz, wz, xz, eio, wo, xo, eig, wg, xg, ws);
        f_final<<<(OUT_TOT + B - 1) / B, B, 0, stream>>>(ws, xz, Wz, bz, xo, Wo, bo, xg, Wg, bg, out);
    }
}